// Round 8
// baseline (185569.226 us; speedup 1.0000x reference)
//
#include <hip/hip_runtime.h>
#include <hip/hip_bf16.h>
#include <stdint.h>

typedef __bf16 bf16_t;
typedef __bf16 bf16x8 __attribute__((ext_vector_type(8)));
typedef float  f32x4  __attribute__((ext_vector_type(4)));

#define HP 514   // padded spatial width (512 + 2)
#define AS1 __attribute__((address_space(1)))
#define AS3 __attribute__((address_space(3)))

__device__ __forceinline__ bf16_t f2bf(float f) { return (bf16_t)f; }

// ---------- L0: 1->64 1x1 conv + PReLU; fp32 NCHW -> padded NHWC bf16 ----------
__global__ void l0_kernel(const float* __restrict__ A, const float* __restrict__ w0,
                          const float* __restrict__ b0, const float* __restrict__ p0,
                          bf16_t* __restrict__ X0)
{
    int idx = blockIdx.x * 256 + threadIdx.x;
    if (idx >= HP * HP * 64) return;
    int c   = idx & 63;
    int pix = idx >> 6;
    int py = pix / HP, px = pix - py * HP;
    float v = 0.f;
    if (py >= 1 && py <= 512 && px >= 1 && px <= 512) {
        float a = A[(py - 1) * 512 + (px - 1)];
        v = fmaf(w0[c], a, b0[c]);
        v = v >= 0.f ? v : p0[0] * v;
    }
    X0[idx] = f2bf(v);
}

// ---------- zero full rows [r0, r0+n) of a strip buffer ----------
__global__ void zero_rows_kernel(bf16_t* __restrict__ buf, int C, int r0, int n)
{
    int idx = blockIdx.x * 256 + threadIdx.x;
    int rowsz = HP * C;
    if (idx >= n * rowsz) return;
    int r = idx / rowsz, j = idx - r * rowsz;
    buf[(size_t)(r0 + r) * rowsz + j] = f2bf(0.f);
}

// ---------- zero cols 0 and 513 for rows [0, R) ----------
__global__ void zero_cols_kernel(bf16_t* __restrict__ buf, int C, int R)
{
    int idx = blockIdx.x * 256 + threadIdx.x;
    if (idx >= R * 2 * C) return;
    int r = idx / (2 * C);
    int t = idx - r * 2 * C;
    int col = (t < C) ? 0 : 513;
    int c = t % C;
    buf[((size_t)r * HP + col) * C + c] = f2bf(0.f);
}

// ---------- weight transform: OIHW fp32 -> MFMA-fragment-ordered bf16 ----------
// wt[(((ci*9 + tap)*G + gabs)*64 + l)*8 + j] = w[(cout*CIN+cin)*9 + tap]
//   cout = gabs*16 + (l&15), cin = ci*32 + (l>>4)*8 + j, G = COUT/16
// (correctness verified R3/R4/R5/R6)
__global__ void wtrans_kernel(const float* __restrict__ w, bf16_t* __restrict__ wt,
                              int COUT, int CIN)
{
    int idx = blockIdx.x * 256 + threadIdx.x;
    if (idx >= COUT * CIN * 9) return;
    int G    = COUT / 16;
    int j    = idx & 7;
    int l    = (idx >> 3) & 63;
    int t    = idx >> 9;
    int gabs = t % G;
    int t2   = t / G;
    int tap  = t2 % 9;
    int ci   = t2 / 9;
    int cout = gabs * 16 + (l & 15);
    int cin  = ci * 32 + (l >> 4) * 8 + j;
    wt[idx] = f2bf(w[(cout * CIN + cin) * 9 + tap]);
}

// ---------- 3x3 conv + bias + PReLU, implicit GEMM, bf16 MFMA ----------
// Block 256 px (16y x 16x) x BN couts, 4 waves (2m x 2n), wave tile 128 px x BN/2.
// A: LDS dbuf, conflict-free swizzled layout (R6-measured 0 conflicts).
// B: REGISTER fragments loaded straight from fragment-ordered global weights,
//    prefetched one tap ahead — NO per-tap barrier. One barrier per 32-ch chunk.
// B double-buffer parity is an EXPLICIT running toggle (bpar): 9 taps/chunk is
// odd, so tap-derived parity breaks at the chunk boundary (R7's bug).
// z-fastest 1D grid pins one cout-block's weights (<=0.6 MB) per XCD L2.
template<int CIN, int COUT, int BN>
__global__ __launch_bounds__(256, 2)
void conv3x3_kernel(const bf16_t* __restrict__ in, const bf16_t* __restrict__ wt,
                    const float* __restrict__ bias, const float* __restrict__ alpha,
                    bf16_t* __restrict__ out,
                    int n_rows, int in_off, int in_alloc, int out_off)
{
    constexpr int G      = COUT / 16;     // global cout groups (wt layout)
    constexpr int GPB    = BN / 16;       // cout groups per block
    constexpr int NT     = GPB / 2;       // n-frags per wave (4 or 2)
    constexpr int NC     = CIN / 32;      // channel chunks
    constexpr int Z      = COUT / BN;     // cout blocks
    constexpr int AUNITS = 18 * 72;       // 1296 16B-units (18r x 18px x 4q)
    constexpr int AROW   = 80;            // unit stride per row (swizzle pad)
    constexpr int ASLAB  = 18 * AROW * 8; // 11520 elems per A buffer
    __shared__ __align__(16) bf16_t As[2 * ASLAB];

    const int tid  = threadIdx.x;
    const int lane = tid & 63;
    const int wave = tid >> 6;
    const int lm   = lane & 15;
    const int quad = lane >> 4;
    const int wave_m = wave >> 1;
    const int wave_n = wave & 1;

    // 1D grid decode, z fastest (XCD round-robin -> constant z per XCD)
    const int bid = blockIdx.x;
    const int zb  = bid % Z;
    const int tb  = bid / Z;
    const int x0  = (tb & 31) * 16;      // input col base (padded coords)
    const int y0  = (tb >> 5) * 16;      // local out row base

    // ---- A staging maps: 1296 units = 5 full passes + 16-unit tail ----
    int a_src[6], a_dst[6];
    #pragma unroll
    for (int it = 0; it < 6; ++it) {
        int u  = it * 256 + tid;
        int uu = u < AUNITS ? u : 0;
        int r = uu / 72, rem = uu - r * 72;
        int px = rem >> 2, q = rem & 3;
        int grow = in_off + y0 + r;
        grow = grow < 0 ? 0 : (grow >= in_alloc ? in_alloc - 1 : grow);
        a_src[it] = (grow * HP + x0 + px) * CIN + q * 8;
        a_dst[it] = (r * AROW + px * 4 + ((q + (px >> 1)) & 3)) * 8;
    }
    const bool tail_ok = (tid < 16);

    // ---- fragment read bases (swizzled) ----
    const int pxl = lm & 7, pyl = lm >> 3;
    int sw[3];
    #pragma unroll
    for (int dx = 0; dx < 3; ++dx)
        sw[dx] = ((quad + ((pxl + dx) >> 1)) & 3) * 8;
    int addrA0[8];
    #pragma unroll
    for (int mt = 0; mt < 8; ++mt) {
        int ry = mt >> 1, rx = mt & 1;
        int row0 = (wave_m * 4 + ry) * 2 + pyl;
        int px0  = rx * 8 + pxl;
        addrA0[mt] = (row0 * AROW + px0 * 4) * 8;
    }

    auto loadA = [&](int cc, bf16x8* s) {
        #pragma unroll
        for (int it = 0; it < 5; ++it) s[it] = *(const bf16x8*)(in + a_src[it] + cc);
        if (tail_ok) s[5] = *(const bf16x8*)(in + a_src[5] + cc);
    };
    auto writeA = [&](const bf16x8* s, int abuf) {
        bf16_t* d = As + abuf * ASLAB;
        #pragma unroll
        for (int it = 0; it < 5; ++it) *(bf16x8*)(d + a_dst[it]) = s[it];
        if (tail_ok) *(bf16x8*)(d + a_dst[5]) = s[5];
    };

    // ---- B register fragments from fragment-ordered global weights ----
    const int gb0 = zb * GPB + wave_n * NT;
    const bf16_t* wbase = wt + (size_t)gb0 * 512 + lane * 8;
    bf16x8 bfrag[2][NT];
    auto loadB = [&](int ci9t, int par) {
        #pragma unroll
        for (int g = 0; g < NT; ++g)
            bfrag[par][g] = *(const bf16x8*)(wbase + ((size_t)ci9t * G + g) * 512);
    };

    f32x4 acc[8][NT] = {};
    bf16x8 areg[6];

    // prologue: chunk-0 A -> buf0, tap-0 B -> bfrag[0]
    loadA(0, areg);
    writeA(areg, 0);
    loadB(0, 0);
    __syncthreads();

    int ab = 0, bpar = 0;
    for (int ci = 0; ci < NC; ++ci) {
        const bool more = (ci + 1 < NC);
        #pragma unroll
        for (int tap = 0; tap < 9; ++tap) {
            // prefetch next tap's (or next chunk's tap-0) B fragments
            if (tap < 8)      loadB(ci * 9 + tap + 1, bpar ^ 1);
            else if (more)    loadB((ci + 1) * 9, bpar ^ 1);
            // prefetch next chunk's A into registers early
            if (tap == 1 && more) loadA((ci + 1) * 32, areg);

            const int dy = tap / 3, dx = tap - dy * 3;
            const int shift = (dy * AROW + dx * 4) * 8 + sw[dx];
            #pragma unroll
            for (int h = 0; h < 2; ++h) {
                bf16x8 a[4];
                #pragma unroll
                for (int j = 0; j < 4; ++j)
                    a[j] = *(const bf16x8*)(As + ab * ASLAB + addrA0[h * 4 + j] + shift);
                #pragma unroll
                for (int j = 0; j < 4; ++j)
                    #pragma unroll
                    for (int nt = 0; nt < NT; ++nt)
                        acc[h * 4 + j][nt] = __builtin_amdgcn_mfma_f32_16x16x32_bf16(
                            a[j], bfrag[bpar][nt], acc[h * 4 + j][nt], 0, 0, 0);
            }
            bpar ^= 1;
        }
        // stage next chunk's A into the other buffer; single barrier per chunk
        if (more) writeA(areg, ab ^ 1);
        __syncthreads();
        ab ^= 1;
    }

    // ---- epilogue: bias + PReLU, bf16 NHWC store (R6-verified mapping) ----
    const float al = alpha[0];
    #pragma unroll
    for (int nt = 0; nt < NT; ++nt) {
        const int n = zb * BN + (wave_n * NT + nt) * 16 + lm;
        const float bv = bias[n];
        #pragma unroll
        for (int mt = 0; mt < 8; ++mt) {
            const int ry = mt >> 1, rx = mt & 1;
            f32x4 v = acc[mt][nt];
            #pragma unroll
            for (int r = 0; r < 4; ++r) {
                int i  = quad * 4 + r;
                int py = (wave_m * 4 + ry) * 2 + (i >> 3);
                int px = rx * 8 + (i & 7);
                int ly = y0 + py;
                if (ly < n_rows) {
                    float f = v[r] + bv;
                    f = f >= 0.f ? f : al * f;
                    out[((size_t)(out_off + ly) * HP + (x0 + px + 1)) * COUT + n] = f2bf(f);
                }
            }
        }
    }
}

// ---------- L5 (64->1, k3) + bias + PReLU per strip, fp32 T out ----------
__device__ __forceinline__ float conv64_at(const bf16_t* __restrict__ X,
                                           const float* __restrict__ wsh,
                                           int y, int x, float bv)
{
    float acc = bv;
    #pragma unroll
    for (int dy = 0; dy < 3; ++dy) {
        #pragma unroll
        for (int dx = 0; dx < 3; ++dx) {
            const bf16x8* p = (const bf16x8*)(X + ((size_t)(y + dy) * HP + (x + dx)) * 64);
            const float* wf = wsh + (dy * 3 + dx) * 64;
            #pragma unroll
            for (int j = 0; j < 8; ++j) {
                bf16x8 v = p[j];
                #pragma unroll
                for (int k = 0; k < 8; ++k)
                    acc = fmaf((float)v[k], wf[j * 8 + k], acc);
            }
        }
    }
    return acc;
}

__global__ __launch_bounds__(256)
void l5_strip_kernel(const bf16_t* __restrict__ B4, const bf16_t* __restrict__ wt5,
                     const float* __restrict__ b5, const float* __restrict__ p5,
                     float* __restrict__ T, int abs_row0)
{
    __shared__ float wsh[9 * 64];
    for (int i = threadIdx.x; i < 576; i += 256) wsh[i] = (float)wt5[i];
    __syncthreads();
    int idx = blockIdx.x * 256 + threadIdx.x;
    int ly = idx >> 9, x = idx & 511;
    float bv = b5[0], al = p5[0];
    float t = conv64_at(B4, wsh, ly, x, bv);
    t = t >= 0.f ? t : al * t;
    T[(size_t)(abs_row0 + ly) * 512 + x] = t;
}

// ---------- weight transform for L5 (plain [tap][cin], tiny) ----------
__global__ void wtrans5_kernel(const float* __restrict__ w, bf16_t* __restrict__ wt)
{
    int idx = blockIdx.x * 256 + threadIdx.x;
    if (idx >= 9 * 64) return;
    int cin = idx % 64, tap = idx / 64;
    wt[idx] = f2bf(w[cin * 9 + tap]);
}

// ---------- final symmetrize ----------
__global__ __launch_bounds__(256)
void sym_kernel(const float* __restrict__ T, float* __restrict__ out)
{
    int idx = blockIdx.x * 256 + threadIdx.x;
    int y = idx >> 9, x = idx & 511;
    out[idx] = 0.5f * (T[idx] + T[x * 512 + y]);
}

// ----------------------------------------------------------------------------
extern "C" void kernel_launch(void* const* d_in, const int* in_sizes, int n_in,
                              void* d_out, int out_size, void* d_ws, size_t ws_size,
                              hipStream_t stream)
{
    const float* A = (const float*)d_in[0];
    const float *w[6], *b[6], *p[6];
    for (int i = 0; i < 6; ++i) {
        w[i] = (const float*)d_in[1 + 3 * i];
        b[i] = (const float*)d_in[2 + 3 * i];
        p[i] = (const float*)d_in[3 + 3 * i];
    }

    auto footprint = [](long long S) -> size_t {
        auto al = [](size_t v) { return (v + 255) & ~(size_t)255; };
        size_t t = 0;
        t += al((size_t)HP * HP * 64 * 2);
        t += al((size_t)(S + 8) * HP * 256 * 2);
        t += al((size_t)(S + 6) * HP * 512 * 2);
        t += al((size_t)(S + 2) * HP * 64 * 2);
        t += al((size_t)512 * 512 * 4);
        t += al((size_t)9 * 256 * 64 * 2);
        t += al((size_t)9 * 512 * 256 * 2);
        t += al((size_t)9 * 256 * 512 * 2);
        t += al((size_t)9 * 64 * 256 * 2);
        t += al((size_t)9 * 64 * 2);
        return t;
    };
    const int cand[6] = {512, 256, 128, 64, 32, 16};
    int S = 16;
    for (int i = 0; i < 6; ++i)
        if (footprint(cand[i]) <= ws_size) { S = cand[i]; break; }
    const int nStrips = 512 / S;

    char* ws = (char*)d_ws;
    size_t off = 0;
    auto carve = [&](size_t bytes) -> void* {
        void* r = ws + off;
        off += (bytes + 255) & ~(size_t)255;
        return r;
    };
    bf16_t* X0  = (bf16_t*)carve((size_t)HP * HP * 64 * 2);
    bf16_t* B1  = (bf16_t*)carve((size_t)(S + 8) * HP * 256 * 2);
    bf16_t* B2  = (bf16_t*)carve((size_t)(S + 6) * HP * 512 * 2);
    bf16_t* B4  = (bf16_t*)carve((size_t)(S + 2) * HP * 64 * 2);
    float*  T   = (float*)carve((size_t)512 * 512 * 4);
    bf16_t* wt1 = (bf16_t*)carve((size_t)9 * 256 * 64 * 2);
    bf16_t* wt2 = (bf16_t*)carve((size_t)9 * 512 * 256 * 2);
    bf16_t* wt3 = (bf16_t*)carve((size_t)9 * 256 * 512 * 2);
    bf16_t* wt4 = (bf16_t*)carve((size_t)9 * 64 * 256 * 2);
    bf16_t* wt5 = (bf16_t*)carve((size_t)9 * 64 * 2);
    bf16_t* B3  = B1;   // alias: B1 dead after each strip's L2

    auto cdiv = [](int a, int bq) { return (a + bq - 1) / bq; };
    auto zrows = [&](bf16_t* buf, int C, int r0, int n) {
        if (n > 0)
            zero_rows_kernel<<<cdiv(n * HP * C, 256), 256, 0, stream>>>(buf, C, r0, n);
    };

    wtrans_kernel<<<cdiv(9 * 256 * 64, 256), 256, 0, stream>>>(w[1], wt1, 256, 64);
    wtrans_kernel<<<cdiv(9 * 512 * 256, 256), 256, 0, stream>>>(w[2], wt2, 512, 256);
    wtrans_kernel<<<cdiv(9 * 256 * 512, 256), 256, 0, stream>>>(w[3], wt3, 256, 512);
    wtrans_kernel<<<cdiv(9 * 64 * 256, 256), 256, 0, stream>>>(w[4], wt4, 64, 256);
    wtrans5_kernel<<<cdiv(9 * 64, 256), 256, 0, stream>>>(w[5], wt5);
    l0_kernel<<<cdiv(HP * HP * 64, 256), 256, 0, stream>>>(A, w[0], b[0], p[0], X0);
    zero_cols_kernel<<<cdiv((S + 8) * 2 * 256, 256), 256, 0, stream>>>(B1, 256, S + 8);
    zero_cols_kernel<<<cdiv((S + 6) * 2 * 512, 256), 256, 0, stream>>>(B2, 512, S + 6);
    zero_cols_kernel<<<cdiv((S + 2) * 2 * 64, 256), 256, 0, stream>>>(B4, 64, S + 2);

    for (int s = 0; s < nStrips; ++s) {
        const int base = S * s;
        int o0[5], nn[5], ooff[5], alloc[5];
        for (int k = 1; k <= 4; ++k) {
            int hk = 5 - k;                      // halos 4,3,2,1
            int a0 = base - hk, a1 = base + S + hk;
            int c0 = a0 < 0 ? 0 : a0, c1 = a1 > 512 ? 512 : a1;
            o0[k] = c0; nn[k] = c1 - c0; ooff[k] = c0 - a0; alloc[k] = S + 2 * hk;
        }
        // L1: X0 -> B1
        {
            int in_off = o0[1];
            conv3x3_kernel<64, 256, 128><<<dim3(32 * cdiv(nn[1], 16) * 2), 256, 0, stream>>>(
                X0, wt1, b[1], p[1], B1, nn[1], in_off, 514, ooff[1]);
            zrows(B1, 256, 0, ooff[1]);
            zrows(B1, 256, ooff[1] + nn[1], alloc[1] - ooff[1] - nn[1]);
        }
        // L2: B1 -> B2
        {
            int in_off = (o0[2] - 1) - (base - 4);
            conv3x3_kernel<256, 512, 128><<<dim3(32 * cdiv(nn[2], 16) * 4), 256, 0, stream>>>(
                B1, wt2, b[2], p[2], B2, nn[2], in_off, alloc[1], ooff[2]);
            zrows(B2, 512, 0, ooff[2]);
            zrows(B2, 512, ooff[2] + nn[2], alloc[2] - ooff[2] - nn[2]);
        }
        // L3: B2 -> B3
        {
            int in_off = (o0[3] - 1) - (base - 3);
            conv3x3_kernel<512, 256, 128><<<dim3(32 * cdiv(nn[3], 16) * 2), 256, 0, stream>>>(
                B2, wt3, b[3], p[3], B3, nn[3], in_off, alloc[2], ooff[3]);
            zrows(B3, 256, 0, ooff[3]);
            zrows(B3, 256, ooff[3] + nn[3], alloc[3] - ooff[3] - nn[3]);
        }
        // L4: B3 -> B4
        {
            int in_off = (o0[4] - 1) - (base - 2);
            conv3x3_kernel<256, 64, 64><<<dim3(32 * cdiv(nn[4], 16) * 1), 256, 0, stream>>>(
                B3, wt4, b[4], p[4], B4, nn[4], in_off, alloc[3], ooff[4]);
            zrows(B4, 64, 0, ooff[4]);
            zrows(B4, 64, ooff[4] + nn[4], alloc[4] - ooff[4] - nn[4]);
        }
        // L5
        l5_strip_kernel<<<(S * 512) / 256, 256, 0, stream>>>(B4, wt5, b[5], p[5], T, base);
    }

    sym_kernel<<<(512 * 512) / 256, 256, 0, stream>>>(T, (float*)d_out);
}

// Round 9
// 2070.292 us; speedup vs baseline: 89.6343x; 89.6343x over previous
//
#include <hip/hip_runtime.h>
#include <hip/hip_bf16.h>
#include <stdint.h>

typedef __bf16 bf16_t;
typedef __bf16 bf16x8 __attribute__((ext_vector_type(8)));
typedef float  f32x4  __attribute__((ext_vector_type(4)));

#define HP 514   // padded spatial width (512 + 2)
#define AS1 __attribute__((address_space(1)))
#define AS3 __attribute__((address_space(3)))

__device__ __forceinline__ bf16_t f2bf(float f) { return (bf16_t)f; }

// ---------- L0: 1->64 1x1 conv + PReLU; fp32 NCHW -> padded NHWC bf16 ----------
__global__ void l0_kernel(const float* __restrict__ A, const float* __restrict__ w0,
                          const float* __restrict__ b0, const float* __restrict__ p0,
                          bf16_t* __restrict__ X0)
{
    int idx = blockIdx.x * 256 + threadIdx.x;
    if (idx >= HP * HP * 64) return;
    int c   = idx & 63;
    int pix = idx >> 6;
    int py = pix / HP, px = pix - py * HP;
    float v = 0.f;
    if (py >= 1 && py <= 512 && px >= 1 && px <= 512) {
        float a = A[(py - 1) * 512 + (px - 1)];
        v = fmaf(w0[c], a, b0[c]);
        v = v >= 0.f ? v : p0[0] * v;
    }
    X0[idx] = f2bf(v);
}

// ---------- zero full rows [r0, r0+n) of a strip buffer ----------
__global__ void zero_rows_kernel(bf16_t* __restrict__ buf, int C, int r0, int n)
{
    int idx = blockIdx.x * 256 + threadIdx.x;
    int rowsz = HP * C;
    if (idx >= n * rowsz) return;
    int r = idx / rowsz, j = idx - r * rowsz;
    buf[(size_t)(r0 + r) * rowsz + j] = f2bf(0.f);
}

// ---------- zero cols 0 and 513 for rows [0, R) ----------
__global__ void zero_cols_kernel(bf16_t* __restrict__ buf, int C, int R)
{
    int idx = blockIdx.x * 256 + threadIdx.x;
    if (idx >= R * 2 * C) return;
    int r = idx / (2 * C);
    int t = idx - r * 2 * C;
    int col = (t < C) ? 0 : 513;
    int c = t % C;
    buf[((size_t)r * HP + col) * C + c] = f2bf(0.f);
}

// ---------- weight transform: OIHW fp32 -> MFMA-fragment-ordered bf16 ----------
// wt[(((ci*9 + tap)*G + gabs)*64 + l)*8 + j] = w[(cout*CIN+cin)*9 + tap]
//   cout = gabs*16 + (l&15), cin = ci*32 + (l>>4)*8 + j, G = COUT/16
// (correctness verified R3..R8)
__global__ void wtrans_kernel(const float* __restrict__ w, bf16_t* __restrict__ wt,
                              int COUT, int CIN)
{
    int idx = blockIdx.x * 256 + threadIdx.x;
    if (idx >= COUT * CIN * 9) return;
    int G    = COUT / 16;
    int j    = idx & 7;
    int l    = (idx >> 3) & 63;
    int t    = idx >> 9;
    int gabs = t % G;
    int t2   = t / G;
    int tap  = t2 % 9;
    int ci   = t2 / 9;
    int cout = gabs * 16 + (l & 15);
    int cin  = ci * 32 + (l >> 4) * 8 + j;
    wt[idx] = f2bf(w[(cout * CIN + cin) * 9 + tap]);
}

// ---------- 3x3 conv + bias + PReLU, implicit GEMM, bf16 MFMA ----------
// Block 256 px (16y x 16x) x BN couts, 4 waves (2m x 2n), wave tile 128 px x BN/2.
// A: LDS dbuf, conflict-free swizzled layout (R6-measured 0 conflicts).
// B: register fragments loaded straight from fragment-ordered global weights,
//    prefetched one tap ahead — NO per-tap barrier; one barrier per 32-ch chunk.
// B rotation uses NAMED registers (bc <- bn copy), never runtime-indexed arrays
// (R8's bfrag[bpar] demoted to scratch -> 100x slowdown).
// z-fastest 1D grid pins one cout-block's weights (<=0.6 MB) per XCD L2.
template<int CIN, int COUT, int BN>
__global__ __launch_bounds__(256, 2)
void conv3x3_kernel(const bf16_t* __restrict__ in, const bf16_t* __restrict__ wt,
                    const float* __restrict__ bias, const float* __restrict__ alpha,
                    bf16_t* __restrict__ out,
                    int n_rows, int in_off, int in_alloc, int out_off)
{
    constexpr int G      = COUT / 16;     // global cout groups (wt layout)
    constexpr int GPB    = BN / 16;       // cout groups per block
    constexpr int NT     = GPB / 2;       // n-frags per wave (4 or 2)
    constexpr int NC     = CIN / 32;      // channel chunks
    constexpr int Z      = COUT / BN;     // cout blocks
    constexpr int AUNITS = 18 * 72;       // 1296 16B-units (18r x 18px x 4q)
    constexpr int AROW   = 80;            // unit stride per row (swizzle pad)
    constexpr int ASLAB  = 18 * AROW * 8; // 11520 elems per A buffer
    __shared__ __align__(16) bf16_t As[2 * ASLAB];

    const int tid  = threadIdx.x;
    const int lane = tid & 63;
    const int lm   = lane & 15;
    const int quad = lane >> 4;
    const int wave   = tid >> 6;
    const int wave_m = wave >> 1;
    const int wave_n = wave & 1;

    // 1D grid decode, z fastest (XCD round-robin -> constant z per XCD)
    const int bid = blockIdx.x;
    const int zb  = bid % Z;
    const int tb  = bid / Z;
    const int x0  = (tb & 31) * 16;      // input col base (padded coords)
    const int y0  = (tb >> 5) * 16;      // local out row base

    // ---- A staging maps: 1296 units = 5 full passes + 16-unit tail ----
    int a_src[6], a_dst[6];
    #pragma unroll
    for (int it = 0; it < 6; ++it) {
        int u  = it * 256 + tid;
        int uu = u < AUNITS ? u : 0;
        int r = uu / 72, rem = uu - r * 72;
        int px = rem >> 2, q = rem & 3;
        int grow = in_off + y0 + r;
        grow = grow < 0 ? 0 : (grow >= in_alloc ? in_alloc - 1 : grow);
        a_src[it] = (grow * HP + x0 + px) * CIN + q * 8;
        a_dst[it] = (r * AROW + px * 4 + ((q + (px >> 1)) & 3)) * 8;
    }
    const bool tail_ok = (tid < 16);

    // ---- fragment read bases (swizzled) ----
    const int pxl = lm & 7, pyl = lm >> 3;
    int sw[3];
    #pragma unroll
    for (int dx = 0; dx < 3; ++dx)
        sw[dx] = ((quad + ((pxl + dx) >> 1)) & 3) * 8;
    int addrA0[8];
    #pragma unroll
    for (int mt = 0; mt < 8; ++mt) {
        int ry = mt >> 1, rx = mt & 1;
        int row0 = (wave_m * 4 + ry) * 2 + pyl;
        int px0  = rx * 8 + pxl;
        addrA0[mt] = (row0 * AROW + px0 * 4) * 8;
    }

    auto loadA = [&](int cc, bf16x8* s) {
        #pragma unroll
        for (int it = 0; it < 5; ++it) s[it] = *(const bf16x8*)(in + a_src[it] + cc);
        if (tail_ok) s[5] = *(const bf16x8*)(in + a_src[5] + cc);
    };
    auto writeA = [&](const bf16x8* s, int abuf) {
        bf16_t* d = As + abuf * ASLAB;
        #pragma unroll
        for (int it = 0; it < 5; ++it) *(bf16x8*)(d + a_dst[it]) = s[it];
        if (tail_ok) *(bf16x8*)(d + a_dst[5]) = s[5];
    };

    // ---- B register fragments from fragment-ordered global weights ----
    const int gb0 = zb * GPB + wave_n * NT;
    const bf16_t* wbase = wt + (size_t)gb0 * 512 + lane * 8;
    bf16x8 bc[NT], bn[NT];
    auto loadB = [&](int ci9t, bf16x8* dst) {
        #pragma unroll
        for (int g = 0; g < NT; ++g)
            dst[g] = *(const bf16x8*)(wbase + ((size_t)ci9t * G + g) * 512);
    };

    f32x4 acc[8][NT] = {};
    bf16x8 areg[6];

    // prologue: chunk-0 A -> buf0, tap-0 B -> bc
    loadA(0, areg);
    writeA(areg, 0);
    loadB(0, bc);
    __syncthreads();

    int ab = 0;
    for (int ci = 0; ci < NC; ++ci) {
        const bool more = (ci + 1 < NC);
        #pragma unroll
        for (int tap = 0; tap < 9; ++tap) {
            // prefetch next tap's (or next chunk's tap-0) B fragments into bn
            if (tap < 8)      loadB(ci * 9 + tap + 1, bn);
            else if (more)    loadB((ci + 1) * 9, bn);
            // prefetch next chunk's A into registers early
            if (tap == 1 && more) loadA((ci + 1) * 32, areg);

            const int dy = tap / 3, dx = tap - dy * 3;
            const int shift = (dy * AROW + dx * 4) * 8 + sw[dx];
            #pragma unroll
            for (int h = 0; h < 2; ++h) {
                bf16x8 a[4];
                #pragma unroll
                for (int j = 0; j < 4; ++j)
                    a[j] = *(const bf16x8*)(As + ab * ASLAB + addrA0[h * 4 + j] + shift);
                #pragma unroll
                for (int j = 0; j < 4; ++j)
                    #pragma unroll
                    for (int nt = 0; nt < NT; ++nt)
                        acc[h * 4 + j][nt] = __builtin_amdgcn_mfma_f32_16x16x32_bf16(
                            a[j], bc[nt], acc[h * 4 + j][nt], 0, 0, 0);
            }
            // rotate named registers (compile-time; renamed away by compiler)
            #pragma unroll
            for (int nt = 0; nt < NT; ++nt) bc[nt] = bn[nt];
        }
        // stage next chunk's A into the other buffer; single barrier per chunk
        if (more) writeA(areg, ab ^ 1);
        __syncthreads();
        ab ^= 1;
    }

    // ---- epilogue: bias + PReLU, bf16 NHWC store (R6-verified mapping) ----
    const float al = alpha[0];
    #pragma unroll
    for (int nt = 0; nt < NT; ++nt) {
        const int n = zb * BN + (wave_n * NT + nt) * 16 + lm;
        const float bv = bias[n];
        #pragma unroll
        for (int mt = 0; mt < 8; ++mt) {
            const int ry = mt >> 1, rx = mt & 1;
            f32x4 v = acc[mt][nt];
            #pragma unroll
            for (int r = 0; r < 4; ++r) {
                int i  = quad * 4 + r;
                int py = (wave_m * 4 + ry) * 2 + (i >> 3);
                int px = rx * 8 + (i & 7);
                int ly = y0 + py;
                if (ly < n_rows) {
                    float f = v[r] + bv;
                    f = f >= 0.f ? f : al * f;
                    out[((size_t)(out_off + ly) * HP + (x0 + px + 1)) * COUT + n] = f2bf(f);
                }
            }
        }
    }
}

// ---------- L5 (64->1, k3) + bias + PReLU per strip, fp32 T out ----------
__device__ __forceinline__ float conv64_at(const bf16_t* __restrict__ X,
                                           const float* __restrict__ wsh,
                                           int y, int x, float bv)
{
    float acc = bv;
    #pragma unroll
    for (int dy = 0; dy < 3; ++dy) {
        #pragma unroll
        for (int dx = 0; dx < 3; ++dx) {
            const bf16x8* p = (const bf16x8*)(X + ((size_t)(y + dy) * HP + (x + dx)) * 64);
            const float* wf = wsh + (dy * 3 + dx) * 64;
            #pragma unroll
            for (int j = 0; j < 8; ++j) {
                bf16x8 v = p[j];
                #pragma unroll
                for (int k = 0; k < 8; ++k)
                    acc = fmaf((float)v[k], wf[j * 8 + k], acc);
            }
        }
    }
    return acc;
}

__global__ __launch_bounds__(256)
void l5_strip_kernel(const bf16_t* __restrict__ B4, const bf16_t* __restrict__ wt5,
                     const float* __restrict__ b5, const float* __restrict__ p5,
                     float* __restrict__ T, int abs_row0)
{
    __shared__ float wsh[9 * 64];
    for (int i = threadIdx.x; i < 576; i += 256) wsh[i] = (float)wt5[i];
    __syncthreads();
    int idx = blockIdx.x * 256 + threadIdx.x;
    int ly = idx >> 9, x = idx & 511;
    float bv = b5[0], al = p5[0];
    float t = conv64_at(B4, wsh, ly, x, bv);
    t = t >= 0.f ? t : al * t;
    T[(size_t)(abs_row0 + ly) * 512 + x] = t;
}

// ---------- weight transform for L5 (plain [tap][cin], tiny) ----------
__global__ void wtrans5_kernel(const float* __restrict__ w, bf16_t* __restrict__ wt)
{
    int idx = blockIdx.x * 256 + threadIdx.x;
    if (idx >= 9 * 64) return;
    int cin = idx % 64, tap = idx / 64;
    wt[idx] = f2bf(w[cin * 9 + tap]);
}

// ---------- final symmetrize ----------
__global__ __launch_bounds__(256)
void sym_kernel(const float* __restrict__ T, float* __restrict__ out)
{
    int idx = blockIdx.x * 256 + threadIdx.x;
    int y = idx >> 9, x = idx & 511;
    out[idx] = 0.5f * (T[idx] + T[x * 512 + y]);
}

// ----------------------------------------------------------------------------
extern "C" void kernel_launch(void* const* d_in, const int* in_sizes, int n_in,
                              void* d_out, int out_size, void* d_ws, size_t ws_size,
                              hipStream_t stream)
{
    const float* A = (const float*)d_in[0];
    const float *w[6], *b[6], *p[6];
    for (int i = 0; i < 6; ++i) {
        w[i] = (const float*)d_in[1 + 3 * i];
        b[i] = (const float*)d_in[2 + 3 * i];
        p[i] = (const float*)d_in[3 + 3 * i];
    }

    auto footprint = [](long long S) -> size_t {
        auto al = [](size_t v) { return (v + 255) & ~(size_t)255; };
        size_t t = 0;
        t += al((size_t)HP * HP * 64 * 2);
        t += al((size_t)(S + 8) * HP * 256 * 2);
        t += al((size_t)(S + 6) * HP * 512 * 2);
        t += al((size_t)(S + 2) * HP * 64 * 2);
        t += al((size_t)512 * 512 * 4);
        t += al((size_t)9 * 256 * 64 * 2);
        t += al((size_t)9 * 512 * 256 * 2);
        t += al((size_t)9 * 256 * 512 * 2);
        t += al((size_t)9 * 64 * 256 * 2);
        t += al((size_t)9 * 64 * 2);
        return t;
    };
    const int cand[6] = {512, 256, 128, 64, 32, 16};
    int S = 16;
    for (int i = 0; i < 6; ++i)
        if (footprint(cand[i]) <= ws_size) { S = cand[i]; break; }
    const int nStrips = 512 / S;

    char* ws = (char*)d_ws;
    size_t off = 0;
    auto carve = [&](size_t bytes) -> void* {
        void* r = ws + off;
        off += (bytes + 255) & ~(size_t)255;
        return r;
    };
    bf16_t* X0  = (bf16_t*)carve((size_t)HP * HP * 64 * 2);
    bf16_t* B1  = (bf16_t*)carve((size_t)(S + 8) * HP * 256 * 2);
    bf16_t* B2  = (bf16_t*)carve((size_t)(S + 6) * HP * 512 * 2);
    bf16_t* B4  = (bf16_t*)carve((size_t)(S + 2) * HP * 64 * 2);
    float*  T   = (float*)carve((size_t)512 * 512 * 4);
    bf16_t* wt1 = (bf16_t*)carve((size_t)9 * 256 * 64 * 2);
    bf16_t* wt2 = (bf16_t*)carve((size_t)9 * 512 * 256 * 2);
    bf16_t* wt3 = (bf16_t*)carve((size_t)9 * 256 * 512 * 2);
    bf16_t* wt4 = (bf16_t*)carve((size_t)9 * 64 * 256 * 2);
    bf16_t* wt5 = (bf16_t*)carve((size_t)9 * 64 * 2);
    bf16_t* B3  = B1;   // alias: B1 dead after each strip's L2

    auto cdiv = [](int a, int bq) { return (a + bq - 1) / bq; };
    auto zrows = [&](bf16_t* buf, int C, int r0, int n) {
        if (n > 0)
            zero_rows_kernel<<<cdiv(n * HP * C, 256), 256, 0, stream>>>(buf, C, r0, n);
    };

    wtrans_kernel<<<cdiv(9 * 256 * 64, 256), 256, 0, stream>>>(w[1], wt1, 256, 64);
    wtrans_kernel<<<cdiv(9 * 512 * 256, 256), 256, 0, stream>>>(w[2], wt2, 512, 256);
    wtrans_kernel<<<cdiv(9 * 256 * 512, 256), 256, 0, stream>>>(w[3], wt3, 256, 512);
    wtrans_kernel<<<cdiv(9 * 64 * 256, 256), 256, 0, stream>>>(w[4], wt4, 64, 256);
    wtrans5_kernel<<<cdiv(9 * 64, 256), 256, 0, stream>>>(w[5], wt5);
    l0_kernel<<<cdiv(HP * HP * 64, 256), 256, 0, stream>>>(A, w[0], b[0], p[0], X0);
    zero_cols_kernel<<<cdiv((S + 8) * 2 * 256, 256), 256, 0, stream>>>(B1, 256, S + 8);
    zero_cols_kernel<<<cdiv((S + 6) * 2 * 512, 256), 256, 0, stream>>>(B2, 512, S + 6);
    zero_cols_kernel<<<cdiv((S + 2) * 2 * 64, 256), 256, 0, stream>>>(B4, 64, S + 2);

    for (int s = 0; s < nStrips; ++s) {
        const int base = S * s;
        int o0[5], nn[5], ooff[5], alloc[5];
        for (int k = 1; k <= 4; ++k) {
            int hk = 5 - k;                      // halos 4,3,2,1
            int a0 = base - hk, a1 = base + S + hk;
            int c0 = a0 < 0 ? 0 : a0, c1 = a1 > 512 ? 512 : a1;
            o0[k] = c0; nn[k] = c1 - c0; ooff[k] = c0 - a0; alloc[k] = S + 2 * hk;
        }
        // L1: X0 -> B1
        {
            int in_off = o0[1];
            conv3x3_kernel<64, 256, 128><<<dim3(32 * cdiv(nn[1], 16) * 2), 256, 0, stream>>>(
                X0, wt1, b[1], p[1], B1, nn[1], in_off, 514, ooff[1]);
            zrows(B1, 256, 0, ooff[1]);
            zrows(B1, 256, ooff[1] + nn[1], alloc[1] - ooff[1] - nn[1]);
        }
        // L2: B1 -> B2
        {
            int in_off = (o0[2] - 1) - (base - 4);
            conv3x3_kernel<256, 512, 128><<<dim3(32 * cdiv(nn[2], 16) * 4), 256, 0, stream>>>(
                B1, wt2, b[2], p[2], B2, nn[2], in_off, alloc[1], ooff[2]);
            zrows(B2, 512, 0, ooff[2]);
            zrows(B2, 512, ooff[2] + nn[2], alloc[2] - ooff[2] - nn[2]);
        }
        // L3: B2 -> B3
        {
            int in_off = (o0[3] - 1) - (base - 3);
            conv3x3_kernel<512, 256, 128><<<dim3(32 * cdiv(nn[3], 16) * 2), 256, 0, stream>>>(
                B2, wt3, b[3], p[3], B3, nn[3], in_off, alloc[2], ooff[3]);
            zrows(B3, 256, 0, ooff[3]);
            zrows(B3, 256, ooff[3] + nn[3], alloc[3] - ooff[3] - nn[3]);
        }
        // L4: B3 -> B4
        {
            int in_off = (o0[4] - 1) - (base - 2);
            conv3x3_kernel<256, 64, 64><<<dim3(32 * cdiv(nn[4], 16) * 1), 256, 0, stream>>>(
                B3, wt4, b[4], p[4], B4, nn[4], in_off, alloc[3], ooff[4]);
            zrows(B4, 64, 0, ooff[4]);
            zrows(B4, 64, ooff[4] + nn[4], alloc[4] - ooff[4] - nn[4]);
        }
        // L5
        l5_strip_kernel<<<(S * 512) / 256, 256, 0, stream>>>(B4, wt5, b[5], p[5], T, base);
    }

    sym_kernel<<<(512 * 512) / 256, 256, 0, stream>>>(T, (float*)d_out);
}

// Round 10
// 1744.754 us; speedup vs baseline: 106.3584x; 1.1866x over previous
//
#include <hip/hip_runtime.h>
#include <hip/hip_bf16.h>
#include <stdint.h>

typedef __bf16 bf16_t;
typedef __bf16 bf16x8 __attribute__((ext_vector_type(8)));
typedef float  f32x4  __attribute__((ext_vector_type(4)));

#define HP 514   // padded spatial width (512 + 2)
#define AS1 __attribute__((address_space(1)))
#define AS3 __attribute__((address_space(3)))

__device__ __forceinline__ bf16_t f2bf(float f) { return (bf16_t)f; }

// ---------- L0: 1->64 1x1 conv + PReLU; fp32 NCHW -> padded NHWC bf16 ----------
__global__ void l0_kernel(const float* __restrict__ A, const float* __restrict__ w0,
                          const float* __restrict__ b0, const float* __restrict__ p0,
                          bf16_t* __restrict__ X0)
{
    int idx = blockIdx.x * 256 + threadIdx.x;
    if (idx >= HP * HP * 64) return;
    int c   = idx & 63;
    int pix = idx >> 6;
    int py = pix / HP, px = pix - py * HP;
    float v = 0.f;
    if (py >= 1 && py <= 512 && px >= 1 && px <= 512) {
        float a = A[(py - 1) * 512 + (px - 1)];
        v = fmaf(w0[c], a, b0[c]);
        v = v >= 0.f ? v : p0[0] * v;
    }
    X0[idx] = f2bf(v);
}

// ---------- zero full rows [r0, r0+n) of a strip buffer ----------
__global__ void zero_rows_kernel(bf16_t* __restrict__ buf, int C, int r0, int n)
{
    int idx = blockIdx.x * 256 + threadIdx.x;
    int rowsz = HP * C;
    if (idx >= n * rowsz) return;
    int r = idx / rowsz, j = idx - r * rowsz;
    buf[(size_t)(r0 + r) * rowsz + j] = f2bf(0.f);
}

// ---------- zero cols 0 and 513 for rows [0, R) ----------
__global__ void zero_cols_kernel(bf16_t* __restrict__ buf, int C, int R)
{
    int idx = blockIdx.x * 256 + threadIdx.x;
    if (idx >= R * 2 * C) return;
    int r = idx / (2 * C);
    int t = idx - r * 2 * C;
    int col = (t < C) ? 0 : 513;
    int c = t % C;
    buf[((size_t)r * HP + col) * C + c] = f2bf(0.f);
}

// ---------- weight transform: OIHW fp32 -> MFMA-fragment-ordered bf16 ----------
// wt[(((ci*9 + tap)*G + gabs)*64 + l)*8 + j] = w[(cout*CIN+cin)*9 + tap]
//   cout = gabs*16 + (l&15), cin = ci*32 + (l>>4)*8 + j, G = COUT/16
// (correctness verified R3..R9)
__global__ void wtrans_kernel(const float* __restrict__ w, bf16_t* __restrict__ wt,
                              int COUT, int CIN)
{
    int idx = blockIdx.x * 256 + threadIdx.x;
    if (idx >= COUT * CIN * 9) return;
    int G    = COUT / 16;
    int j    = idx & 7;
    int l    = (idx >> 3) & 63;
    int t    = idx >> 9;
    int gabs = t % G;
    int t2   = t / G;
    int tap  = t2 % 9;
    int ci   = t2 / 9;
    int cout = gabs * 16 + (l & 15);
    int cin  = ci * 32 + (l >> 4) * 8 + j;
    wt[idx] = f2bf(w[(cout * CIN + cin) * 9 + tap]);
}

// ---------- 3x3 conv + bias + PReLU, implicit GEMM, bf16 MFMA ----------
// Block 256 px (16y x 16x) x BN couts, 4 waves (2m x 2n), wave tile 128 px x BN/2.
// A: LDS dbuf, conflict-free swizzled layout (R6/R9-measured 0 conflicts).
// B: register fragments from fragment-ordered global weights, prefetched one tap
//    ahead with NAMED rotation (bc <- bn); one barrier per 32-ch chunk.
// R10: BN=64 for all big layers -> acc=64 AGPR (was 128) -> ~159 unified regs
//      -> 3 waves/SIMD (R9's 256 regs capped at 2 and stalled at MfmaUtil 32%).
// z-fastest 1D grid pins one cout-block's weights per XCD L2 (L2 layer: Z=8 = #XCDs).
template<int CIN, int COUT, int BN>
__global__ __launch_bounds__(256, 2)
void conv3x3_kernel(const bf16_t* __restrict__ in, const bf16_t* __restrict__ wt,
                    const float* __restrict__ bias, const float* __restrict__ alpha,
                    bf16_t* __restrict__ out,
                    int n_rows, int in_off, int in_alloc, int out_off)
{
    constexpr int G      = COUT / 16;     // global cout groups (wt layout)
    constexpr int GPB    = BN / 16;       // cout groups per block
    constexpr int NT     = GPB / 2;       // n-frags per wave
    constexpr int NC     = CIN / 32;      // channel chunks
    constexpr int Z      = COUT / BN;     // cout blocks
    constexpr int AUNITS = 18 * 72;       // 1296 16B-units (18r x 18px x 4q)
    constexpr int AROW   = 80;            // unit stride per row (swizzle pad)
    constexpr int ASLAB  = 18 * AROW * 8; // 11520 elems per A buffer
    __shared__ __align__(16) bf16_t As[2 * ASLAB];

    const int tid  = threadIdx.x;
    const int lane = tid & 63;
    const int lm   = lane & 15;
    const int quad = lane >> 4;
    const int wave   = tid >> 6;
    const int wave_m = wave >> 1;
    const int wave_n = wave & 1;

    // 1D grid decode, z fastest (XCD round-robin -> constant z per XCD)
    const int bid = blockIdx.x;
    const int zb  = bid % Z;
    const int tb  = bid / Z;
    const int x0  = (tb & 31) * 16;      // input col base (padded coords)
    const int y0  = (tb >> 5) * 16;      // local out row base

    // ---- A staging maps: 1296 units = 5 full passes + 16-unit tail ----
    int a_src[6], a_dst[6];
    #pragma unroll
    for (int it = 0; it < 6; ++it) {
        int u  = it * 256 + tid;
        int uu = u < AUNITS ? u : 0;
        int r = uu / 72, rem = uu - r * 72;
        int px = rem >> 2, q = rem & 3;
        int grow = in_off + y0 + r;
        grow = grow < 0 ? 0 : (grow >= in_alloc ? in_alloc - 1 : grow);
        a_src[it] = (grow * HP + x0 + px) * CIN + q * 8;
        a_dst[it] = (r * AROW + px * 4 + ((q + (px >> 1)) & 3)) * 8;
    }
    const bool tail_ok = (tid < 16);

    // ---- fragment read bases (swizzled) ----
    const int pxl = lm & 7, pyl = lm >> 3;
    int sw[3];
    #pragma unroll
    for (int dx = 0; dx < 3; ++dx)
        sw[dx] = ((quad + ((pxl + dx) >> 1)) & 3) * 8;
    int addrA0[8];
    #pragma unroll
    for (int mt = 0; mt < 8; ++mt) {
        int ry = mt >> 1, rx = mt & 1;
        int row0 = (wave_m * 4 + ry) * 2 + pyl;
        int px0  = rx * 8 + pxl;
        addrA0[mt] = (row0 * AROW + px0 * 4) * 8;
    }

    auto loadA = [&](int cc, bf16x8* s) {
        #pragma unroll
        for (int it = 0; it < 5; ++it) s[it] = *(const bf16x8*)(in + a_src[it] + cc);
        if (tail_ok) s[5] = *(const bf16x8*)(in + a_src[5] + cc);
    };
    auto writeA = [&](const bf16x8* s, int abuf) {
        bf16_t* d = As + abuf * ASLAB;
        #pragma unroll
        for (int it = 0; it < 5; ++it) *(bf16x8*)(d + a_dst[it]) = s[it];
        if (tail_ok) *(bf16x8*)(d + a_dst[5]) = s[5];
    };

    // ---- B register fragments from fragment-ordered global weights ----
    const int gb0 = zb * GPB + wave_n * NT;
    const bf16_t* wbase = wt + (size_t)gb0 * 512 + lane * 8;
    bf16x8 bc[NT], bn[NT];
    auto loadB = [&](int ci9t, bf16x8* dst) {
        #pragma unroll
        for (int g = 0; g < NT; ++g)
            dst[g] = *(const bf16x8*)(wbase + ((size_t)ci9t * G + g) * 512);
    };

    f32x4 acc[8][NT] = {};
    bf16x8 areg[6];

    // prologue: chunk-0 A -> buf0, tap-0 B -> bc
    loadA(0, areg);
    writeA(areg, 0);
    loadB(0, bc);
    __syncthreads();

    int ab = 0;
    for (int ci = 0; ci < NC; ++ci) {
        const bool more = (ci + 1 < NC);
        #pragma unroll
        for (int tap = 0; tap < 9; ++tap) {
            // prefetch next tap's (or next chunk's tap-0) B fragments into bn
            if (tap < 8)      loadB(ci * 9 + tap + 1, bn);
            else if (more)    loadB((ci + 1) * 9, bn);
            // prefetch next chunk's A into registers early
            if (tap == 1 && more) loadA((ci + 1) * 32, areg);

            const int dy = tap / 3, dx = tap - dy * 3;
            const int shift = (dy * AROW + dx * 4) * 8 + sw[dx];
            #pragma unroll
            for (int h = 0; h < 2; ++h) {
                bf16x8 a[4];
                #pragma unroll
                for (int j = 0; j < 4; ++j)
                    a[j] = *(const bf16x8*)(As + ab * ASLAB + addrA0[h * 4 + j] + shift);
                #pragma unroll
                for (int j = 0; j < 4; ++j)
                    #pragma unroll
                    for (int nt = 0; nt < NT; ++nt)
                        acc[h * 4 + j][nt] = __builtin_amdgcn_mfma_f32_16x16x32_bf16(
                            a[j], bc[nt], acc[h * 4 + j][nt], 0, 0, 0);
            }
            // rotate named registers (compile-time; renamed away by compiler)
            #pragma unroll
            for (int nt = 0; nt < NT; ++nt) bc[nt] = bn[nt];
        }
        // stage next chunk's A into the other buffer; single barrier per chunk
        if (more) writeA(areg, ab ^ 1);
        __syncthreads();
        ab ^= 1;
    }

    // ---- epilogue: bias + PReLU, bf16 NHWC store (R6/R9-verified mapping) ----
    const float al = alpha[0];
    #pragma unroll
    for (int nt = 0; nt < NT; ++nt) {
        const int n = zb * BN + (wave_n * NT + nt) * 16 + lm;
        const float bv = bias[n];
        #pragma unroll
        for (int mt = 0; mt < 8; ++mt) {
            const int ry = mt >> 1, rx = mt & 1;
            f32x4 v = acc[mt][nt];
            #pragma unroll
            for (int r = 0; r < 4; ++r) {
                int i  = quad * 4 + r;
                int py = (wave_m * 4 + ry) * 2 + (i >> 3);
                int px = rx * 8 + (i & 7);
                int ly = y0 + py;
                if (ly < n_rows) {
                    float f = v[r] + bv;
                    f = f >= 0.f ? f : al * f;
                    out[((size_t)(out_off + ly) * HP + (x0 + px + 1)) * COUT + n] = f2bf(f);
                }
            }
        }
    }
}

// ---------- L5 (64->1, k3) + bias + PReLU per strip, fp32 T out ----------
__device__ __forceinline__ float conv64_at(const bf16_t* __restrict__ X,
                                           const float* __restrict__ wsh,
                                           int y, int x, float bv)
{
    float acc = bv;
    #pragma unroll
    for (int dy = 0; dy < 3; ++dy) {
        #pragma unroll
        for (int dx = 0; dx < 3; ++dx) {
            const bf16x8* p = (const bf16x8*)(X + ((size_t)(y + dy) * HP + (x + dx)) * 64);
            const float* wf = wsh + (dy * 3 + dx) * 64;
            #pragma unroll
            for (int j = 0; j < 8; ++j) {
                bf16x8 v = p[j];
                #pragma unroll
                for (int k = 0; k < 8; ++k)
                    acc = fmaf((float)v[k], wf[j * 8 + k], acc);
            }
        }
    }
    return acc;
}

__global__ __launch_bounds__(256)
void l5_strip_kernel(const bf16_t* __restrict__ B4, const bf16_t* __restrict__ wt5,
                     const float* __restrict__ b5, const float* __restrict__ p5,
                     float* __restrict__ T, int abs_row0)
{
    __shared__ float wsh[9 * 64];
    for (int i = threadIdx.x; i < 576; i += 256) wsh[i] = (float)wt5[i];
    __syncthreads();
    int idx = blockIdx.x * 256 + threadIdx.x;
    int ly = idx >> 9, x = idx & 511;
    float bv = b5[0], al = p5[0];
    float t = conv64_at(B4, wsh, ly, x, bv);
    t = t >= 0.f ? t : al * t;
    T[(size_t)(abs_row0 + ly) * 512 + x] = t;
}

// ---------- weight transform for L5 (plain [tap][cin], tiny) ----------
__global__ void wtrans5_kernel(const float* __restrict__ w, bf16_t* __restrict__ wt)
{
    int idx = blockIdx.x * 256 + threadIdx.x;
    if (idx >= 9 * 64) return;
    int cin = idx % 64, tap = idx / 64;
    wt[idx] = f2bf(w[cin * 9 + tap]);
}

// ---------- final symmetrize ----------
__global__ __launch_bounds__(256)
void sym_kernel(const float* __restrict__ T, float* __restrict__ out)
{
    int idx = blockIdx.x * 256 + threadIdx.x;
    int y = idx >> 9, x = idx & 511;
    out[idx] = 0.5f * (T[idx] + T[x * 512 + y]);
}

// ----------------------------------------------------------------------------
extern "C" void kernel_launch(void* const* d_in, const int* in_sizes, int n_in,
                              void* d_out, int out_size, void* d_ws, size_t ws_size,
                              hipStream_t stream)
{
    const float* A = (const float*)d_in[0];
    const float *w[6], *b[6], *p[6];
    for (int i = 0; i < 6; ++i) {
        w[i] = (const float*)d_in[1 + 3 * i];
        b[i] = (const float*)d_in[2 + 3 * i];
        p[i] = (const float*)d_in[3 + 3 * i];
    }

    auto footprint = [](long long S) -> size_t {
        auto al = [](size_t v) { return (v + 255) & ~(size_t)255; };
        size_t t = 0;
        t += al((size_t)HP * HP * 64 * 2);
        t += al((size_t)(S + 8) * HP * 256 * 2);
        t += al((size_t)(S + 6) * HP * 512 * 2);
        t += al((size_t)(S + 2) * HP * 64 * 2);
        t += al((size_t)512 * 512 * 4);
        t += al((size_t)9 * 256 * 64 * 2);
        t += al((size_t)9 * 512 * 256 * 2);
        t += al((size_t)9 * 256 * 512 * 2);
        t += al((size_t)9 * 64 * 256 * 2);
        t += al((size_t)9 * 64 * 2);
        return t;
    };
    const int cand[6] = {512, 256, 128, 64, 32, 16};
    int S = 16;
    for (int i = 0; i < 6; ++i)
        if (footprint(cand[i]) <= ws_size) { S = cand[i]; break; }
    const int nStrips = 512 / S;

    char* ws = (char*)d_ws;
    size_t off = 0;
    auto carve = [&](size_t bytes) -> void* {
        void* r = ws + off;
        off += (bytes + 255) & ~(size_t)255;
        return r;
    };
    bf16_t* X0  = (bf16_t*)carve((size_t)HP * HP * 64 * 2);
    bf16_t* B1  = (bf16_t*)carve((size_t)(S + 8) * HP * 256 * 2);
    bf16_t* B2  = (bf16_t*)carve((size_t)(S + 6) * HP * 512 * 2);
    bf16_t* B4  = (bf16_t*)carve((size_t)(S + 2) * HP * 64 * 2);
    float*  T   = (float*)carve((size_t)512 * 512 * 4);
    bf16_t* wt1 = (bf16_t*)carve((size_t)9 * 256 * 64 * 2);
    bf16_t* wt2 = (bf16_t*)carve((size_t)9 * 512 * 256 * 2);
    bf16_t* wt3 = (bf16_t*)carve((size_t)9 * 256 * 512 * 2);
    bf16_t* wt4 = (bf16_t*)carve((size_t)9 * 64 * 256 * 2);
    bf16_t* wt5 = (bf16_t*)carve((size_t)9 * 64 * 2);
    bf16_t* B3  = B1;   // alias: B1 dead after each strip's L2

    auto cdiv = [](int a, int bq) { return (a + bq - 1) / bq; };
    auto zrows = [&](bf16_t* buf, int C, int r0, int n) {
        if (n > 0)
            zero_rows_kernel<<<cdiv(n * HP * C, 256), 256, 0, stream>>>(buf, C, r0, n);
    };

    wtrans_kernel<<<cdiv(9 * 256 * 64, 256), 256, 0, stream>>>(w[1], wt1, 256, 64);
    wtrans_kernel<<<cdiv(9 * 512 * 256, 256), 256, 0, stream>>>(w[2], wt2, 512, 256);
    wtrans_kernel<<<cdiv(9 * 256 * 512, 256), 256, 0, stream>>>(w[3], wt3, 256, 512);
    wtrans_kernel<<<cdiv(9 * 64 * 256, 256), 256, 0, stream>>>(w[4], wt4, 64, 256);
    wtrans5_kernel<<<cdiv(9 * 64, 256), 256, 0, stream>>>(w[5], wt5);
    l0_kernel<<<cdiv(HP * HP * 64, 256), 256, 0, stream>>>(A, w[0], b[0], p[0], X0);
    zero_cols_kernel<<<cdiv((S + 8) * 2 * 256, 256), 256, 0, stream>>>(B1, 256, S + 8);
    zero_cols_kernel<<<cdiv((S + 6) * 2 * 512, 256), 256, 0, stream>>>(B2, 512, S + 6);
    zero_cols_kernel<<<cdiv((S + 2) * 2 * 64, 256), 256, 0, stream>>>(B4, 64, S + 2);

    for (int s = 0; s < nStrips; ++s) {
        const int base = S * s;
        int o0[5], nn[5], ooff[5], alloc[5];
        for (int k = 1; k <= 4; ++k) {
            int hk = 5 - k;                      // halos 4,3,2,1
            int a0 = base - hk, a1 = base + S + hk;
            int c0 = a0 < 0 ? 0 : a0, c1 = a1 > 512 ? 512 : a1;
            o0[k] = c0; nn[k] = c1 - c0; ooff[k] = c0 - a0; alloc[k] = S + 2 * hk;
        }
        // L1: X0 -> B1  (BN=64 -> Z=4)
        {
            int in_off = o0[1];
            conv3x3_kernel<64, 256, 64><<<dim3(32 * cdiv(nn[1], 16) * 4), 256, 0, stream>>>(
                X0, wt1, b[1], p[1], B1, nn[1], in_off, 514, ooff[1]);
            zrows(B1, 256, 0, ooff[1]);
            zrows(B1, 256, ooff[1] + nn[1], alloc[1] - ooff[1] - nn[1]);
        }
        // L2: B1 -> B2  (BN=64 -> Z=8 = #XCDs)
        {
            int in_off = (o0[2] - 1) - (base - 4);
            conv3x3_kernel<256, 512, 64><<<dim3(32 * cdiv(nn[2], 16) * 8), 256, 0, stream>>>(
                B1, wt2, b[2], p[2], B2, nn[2], in_off, alloc[1], ooff[2]);
            zrows(B2, 512, 0, ooff[2]);
            zrows(B2, 512, ooff[2] + nn[2], alloc[2] - ooff[2] - nn[2]);
        }
        // L3: B2 -> B3  (BN=64 -> Z=4)
        {
            int in_off = (o0[3] - 1) - (base - 3);
            conv3x3_kernel<512, 256, 64><<<dim3(32 * cdiv(nn[3], 16) * 4), 256, 0, stream>>>(
                B2, wt3, b[3], p[3], B3, nn[3], in_off, alloc[2], ooff[3]);
            zrows(B3, 256, 0, ooff[3]);
            zrows(B3, 256, ooff[3] + nn[3], alloc[3] - ooff[3] - nn[3]);
        }
        // L4: B3 -> B4  (BN=64 -> Z=1)
        {
            int in_off = (o0[4] - 1) - (base - 2);
            conv3x3_kernel<256, 64, 64><<<dim3(32 * cdiv(nn[4], 16) * 1), 256, 0, stream>>>(
                B3, wt4, b[4], p[4], B4, nn[4], in_off, alloc[3], ooff[4]);
            zrows(B4, 64, 0, ooff[4]);
            zrows(B4, 64, ooff[4] + nn[4], alloc[4] - ooff[4] - nn[4]);
        }
        // L5
        l5_strip_kernel<<<(S * 512) / 256, 256, 0, stream>>>(B4, wt5, b[5], p[5], T, base);
    }

    sym_kernel<<<(512 * 512) / 256, 256, 0, stream>>>(T, (float*)d_out);
}